// Round 13
// baseline (178.998 us; speedup 1.0000x reference)
//
#include <hip/hip_runtime.h>

// LBP uniform P=8 R=1 on (32,3,512,512) f32, zero-padded borders.
// R9: grid-stride PERSISTENT waves x champion R6 one-shot body.
// Evidence: R3(51)=R6(51) < R8 shuffle(65) < R7 pipelined(67) < R4 LDS(68)
// < R5(84). VMEM mix, VALU count, occupancy, traffic all falsified as
// limiters (nulls); no pipe >33% busy. Remaining suspect: dispatch ramp +
// one-shot wave churn (24-48K short waves, grid drains/refills 24 deep).
// R9: 2048 blocks (G11 cap), each thread does 6 iterations with work-id
// stride 2^19 -> identical row/col bitfields, plane += 16 per iter
// (coalescing unchanged, no tail). Ramp paid once; iter i+1 loads overlap
// iter i store drain. Body is R6 verbatim: 2x4 px/thread, 4 clamped-row
// loads (float4 + 2 edge scalars), floor-trick (neighbors unfloored),
// wave-uniform row scale, nt stores.

#define LBP_H 512
#define LBP_W 512
#define NPLANES 96           // 32 * 3

typedef float f32x4 __attribute__((ext_vector_type(4)));

__global__ __launch_bounds__(256, 8) void lbp_kernel(const float* __restrict__ x,
                                                     float* __restrict__ out) {
    const int tid = blockIdx.x * 256 + threadIdx.x;   // 0..524287

    for (int it = 0; it < 6; ++it) {
        const int idx   = tid + (it << 19);
        const int col4  = idx & 127;          // cols j0..j0+3
        const int rowg  = (idx >> 7) & 255;   // rows r0..r0+1
        const int plane = idx >> 15;          // 0..95
        const int j0 = col4 << 2;
        const int r0 = rowg << 1;

        const float* base  = x   + (size_t)plane * (LBP_H * LBP_W);
        float*       obase = out + (size_t)plane * (LBP_H * LBP_W);

        const int jm1 = (j0 > 0)         ? j0 - 1 : 0;
        const int jp4 = (j0 + 4 < LBP_W) ? j0 + 4 : LBP_W - 1;
        const bool lok = (j0 > 0);
        const bool rok = (j0 + 4 < LBP_W);

        // ---- phase 1: all 12 loads issued back-to-back, clamped rows ----
        f32x4 v[4];
        float lf[4], rt[4];
#pragma unroll
        for (int r = 0; r < 4; ++r) {
            int ri  = r0 - 1 + r;
            int ric = ri < 0 ? 0 : (ri >= LBP_H ? LBP_H - 1 : ri);
            const float* rp = base + ric * LBP_W;
            v[r]  = *(const f32x4*)(rp + j0);   // aligned 16B, coalesced
            lf[r] = rp[jm1];
            rt[r] = rp[jp4];
        }

        // ---- phase 2: m = value*255, row mask folded into scale ----
        float m[4][6];
#pragma unroll
        for (int r = 0; r < 4; ++r) {
            const int ri = r0 - 1 + r;
            const float rs = ((unsigned)ri < LBP_H) ? 255.0f : 0.0f;
            m[r][0] = lok ? lf[r] * rs : 0.0f;
            m[r][1] = v[r].x * rs;
            m[r][2] = v[r].y * rs;
            m[r][3] = v[r].z * rs;
            m[r][4] = v[r].w * rs;
            m[r][5] = rok ? rt[r] * rs : 0.0f;
        }

        // ---- phase 3: 8 LBP codes, 2 coalesced nt stores ----
#pragma unroll
        for (int p = 0; p < 2; ++p) {
            f32x4 o;
#pragma unroll
            for (int c = 0; c < 4; ++c) {
                const float q = floorf(m[p + 1][c + 1]);   // center, integer
                unsigned msk = 0u;
                msk |= (m[p    ][c    ] >= q) ?   1u : 0u;
                msk |= (m[p    ][c + 1] >= q) ?   2u : 0u;
                msk |= (m[p    ][c + 2] >= q) ?   4u : 0u;
                msk |= (m[p + 1][c + 2] >= q) ?   8u : 0u;
                msk |= (m[p + 2][c + 2] >= q) ?  16u : 0u;
                msk |= (m[p + 2][c + 1] >= q) ?  32u : 0u;
                msk |= (m[p + 2][c    ] >= q) ?  64u : 0u;
                msk |= (m[p + 1][c    ] >= q) ? 128u : 0u;
                const unsigned rot = ((msk >> 1) | (msk << 7)) & 255u;
                const int trans = __popc(msk ^ rot);
                const int val = (trans <= 2) ? __popc(msk) : 9;
                o[c] = (float)val * (1.0f / 255.0f);
            }
            __builtin_nontemporal_store(
                o, (f32x4*)(obase + (size_t)(r0 + p) * LBP_W + j0));
        }
    }
}

extern "C" void kernel_launch(void* const* d_in, const int* in_sizes, int n_in,
                              void* d_out, int out_size, void* d_ws, size_t ws_size,
                              hipStream_t stream) {
    const float* x = (const float*)d_in[0];
    float* out = (float*)d_out;
    // 2048 persistent blocks x 256 threads; 6 grid-stride iterations cover
    // 96 planes x 256 row-pairs x 128 col-quads = 3,145,728 work items.
    lbp_kernel<<<2048, 256, 0, stream>>>(x, out);
}

// Round 14
// 171.631 us; speedup vs baseline: 1.0429x; 1.0429x over previous
//
#include <hip/hip_runtime.h>

// LBP uniform P=8 R=1 on (32,3,512,512) f32, zero-padded borders.
// FINAL (R10 = champion R3 restored verbatim, best measured: 170.35us).
// Session falsification matrix (kernel-only us, dur = kernel + ~119us
// harness fills): R3/R6 one-shot ~51 < R9 persistent 62 < R8 shuffle 65
// < R7 pipelined 67.5 < R4 LDS 68 < R5 84.
//   - traffic: compulsory in every variant (FETCH 49-93MB L3-dependent,
//     WRITE ~98MB) -> not the lever.
//   - VALU: R6 cut ~30% -> null. occupancy: R6 doubled -> null.
//   - VMEM mix: R8 removed all 12 scalar gathers -> hurt (shuffle lgkm
//     chains on critical path).
//   - pipelining: R5/R7 both collapsed by compiler (VGPR=40), LDS variant
//     barrier-convoyed -> hurt.
//   - persistence: R9 -> hurt.
// No pipe ever >36% busy: latency-structural floor ~3.9 TB/s effective
// mixed-stream for 200MB r+w. Simplest one-shot structure sits closest.
// R3: 4x4 output tile per thread; ALL 18 global loads (6 float4 rows + 12
// clamped edge scalars) issued back-to-back -> single vmcnt exposure;
// bounds via address clamping + zero-masking after load.

#define LBP_H 512
#define LBP_W 512
#define NPLANES 96           // 32 * 3

__device__ __forceinline__ float lbp_quant(float v) {
    // == jnp.clip(jnp.floor(x*255), 0, 255) in exact fp32 arithmetic
    return fminf(fmaxf(floorf(v * 255.0f), 0.0f), 255.0f);
}

__global__ __launch_bounds__(256) void lbp_kernel(const float* __restrict__ x,
                                                  float* __restrict__ out) {
    const int idx  = blockIdx.x * blockDim.x + threadIdx.x;
    const int col4  = idx & 127;          // 0..127  (columns j0..j0+3)
    const int rowg  = (idx >> 7) & 127;   // 0..127  (rows r0..r0+3)
    const int plane = idx >> 14;          // 0..95   (b*C + c)
    const int j0 = col4 << 2;
    const int r0 = rowg << 2;

    const float* base  = x   + (size_t)plane * (LBP_H * LBP_W);
    float*       obase = out + (size_t)plane * (LBP_H * LBP_W);

    const int jm1 = (j0 > 0)           ? j0 - 1 : 0;        // clamped left col
    const int jp4 = (j0 + 4 < LBP_W)   ? j0 + 4 : LBP_W - 1; // clamped right col
    const bool lok = (j0 > 0);
    const bool rok = (j0 + 4 < LBP_W);

    // ---- phase 1: issue ALL loads, addresses clamped, no dependent ALU ----
    float4 v[6];
    float lf[6], rt[6];
#pragma unroll
    for (int r = 0; r < 6; ++r) {
        int ri = r0 - 1 + r;
        int ric = ri < 0 ? 0 : (ri >= LBP_H ? LBP_H - 1 : ri);
        const float* rp = base + ric * LBP_W;
        v[r]  = *(const float4*)(rp + j0);   // aligned 16B, coalesced
        lf[r] = rp[jm1];
        rt[r] = rp[jp4];
    }

    // ---- phase 2: quantize once per value, mask out-of-image to 0 ----
    // e[r][k]: quantized value at input row r0-1+r, col j0-1+k (0 outside)
    float e[6][6];
#pragma unroll
    for (int r = 0; r < 6; ++r) {
        const int ri = r0 - 1 + r;
        const bool rv = (ri >= 0) && (ri < LBP_H);
        e[r][0] = (rv && lok) ? lbp_quant(lf[r]) : 0.0f;
        e[r][1] = rv ? lbp_quant(v[r].x) : 0.0f;
        e[r][2] = rv ? lbp_quant(v[r].y) : 0.0f;
        e[r][3] = rv ? lbp_quant(v[r].z) : 0.0f;
        e[r][4] = rv ? lbp_quant(v[r].w) : 0.0f;
        e[r][5] = (rv && rok) ? lbp_quant(rt[r]) : 0.0f;
    }

    // ---- phase 3: 16 LBP codes ----
#pragma unroll
    for (int p = 0; p < 4; ++p) {             // output row r0+p
        float4 o;
        float* op = &o.x;
#pragma unroll
        for (int c = 0; c < 4; ++c) {         // output col j0+c
            const float ctr = e[p + 1][c + 1];
            // circular order: (-1,-1),(-1,0),(-1,1),(0,1),(1,1),(1,0),(1,-1),(0,-1)
            unsigned m = 0u;
            m |= (e[p    ][c    ] >= ctr) ?   1u : 0u;
            m |= (e[p    ][c + 1] >= ctr) ?   2u : 0u;
            m |= (e[p    ][c + 2] >= ctr) ?   4u : 0u;
            m |= (e[p + 1][c + 2] >= ctr) ?   8u : 0u;
            m |= (e[p + 2][c + 2] >= ctr) ?  16u : 0u;
            m |= (e[p + 2][c + 1] >= ctr) ?  32u : 0u;
            m |= (e[p + 2][c    ] >= ctr) ?  64u : 0u;
            m |= (e[p + 1][c    ] >= ctr) ? 128u : 0u;
            const unsigned rot = ((m >> 1) | (m << 7)) & 255u;
            const int trans = __popc(m ^ rot);
            const int val = (trans <= 2) ? __popc(m) : 9;
            op[c] = (float)val * (1.0f / 255.0f);
        }
        *(float4*)(obase + (size_t)(r0 + p) * LBP_W + j0) = o;
    }
}

extern "C" void kernel_launch(void* const* d_in, const int* in_sizes, int n_in,
                              void* d_out, int out_size, void* d_ws, size_t ws_size,
                              hipStream_t stream) {
    const float* x = (const float*)d_in[0];
    float* out = (float*)d_out;
    const int total = NPLANES * 128 * 128;        // 1,572,864 threads (16 px each)
    const int threads = 256;
    const int blocks = total / threads;           // 6144
    lbp_kernel<<<blocks, threads, 0, stream>>>(x, out);
}